// Round 1
// baseline (382.614 us; speedup 1.0000x reference)
//
#include <hip/hip_runtime.h>
#include <hip/hip_bf16.h>

// SynthesisConv: style affine -> demod -> conv_transpose(up=2,k=3) -> FIR 4x4
// -> noise + bias + lrelu*sqrt(2) + clamp(+-256).  Inputs f32, output f32.
//
//   style folds into x (B-operand column scale), dcoef folds into epilogue.
//   Z[(o,ky,kx),(b,i,j)] = sum_c w[o,c,ky,kx] * x'[b,c,i,j]   (one shared GEMM)
// R7: k_gemm LDS chunk-swizzle kills the 8-way ds_read_b128 bank conflict.
// R8: k_gemm rebuilt as 256x256 tile, BK=32, 4-buffer LDS ring (128 KiB),
//     8 waves (2Mx4N), 2 phases/K-tile, counted s_waitcnt vmcnt(4) (never 0
//     in steady state), raw s_barrier (no vmcnt drain), setprio around MFMA.
//     Same chunk swizzle on stage-source + read side -> numerics identical.

typedef unsigned short u16;
typedef unsigned int u32;
typedef u16 u16x8 __attribute__((ext_vector_type(8)));
typedef __bf16 bf16x8 __attribute__((ext_vector_type(8)));
typedef float f32x4 __attribute__((ext_vector_type(4)));

#define NB 16

__device__ __forceinline__ float bf2f(u16 v) {
  unsigned int u = ((unsigned int)v) << 16;
  float f;
  __builtin_memcpy(&f, &u, 4);
  return f;
}
__device__ __forceinline__ u16 f2bf(float f) {
  __hip_bfloat16 h = __float2bfloat16(f);  // RNE
  u16 r;
  __builtin_memcpy(&r, &h, 2);
  return r;
}
__device__ __forceinline__ void async16(u16* lds, const u16* g) {
  __builtin_amdgcn_global_load_lds(
      (const __attribute__((address_space(1))) u32*)g,
      (__attribute__((address_space(3))) u32*)lds, 16, 0, 0);
}

// ---- style[b,c] = sum_k wl[b,k]*aw[c,k]/sqrt(512) + ab[c] ---------------------
__global__ __launch_bounds__(256) void k_style(const float* __restrict__ wl,
                                               const float* __restrict__ aw,
                                               const float* __restrict__ ab,
                                               float* __restrict__ style) {
  __shared__ float lw[512];
  const int b = blockIdx.y;
  const int c = blockIdx.x * 256 + threadIdx.x;
  for (int k = threadIdx.x; k < 512; k += 256) lw[k] = wl[b * 512 + k];
  __syncthreads();
  const float* row = aw + (size_t)c * 512;
  float acc = 0.f;
#pragma unroll 8
  for (int k = 0; k < 512; ++k) acc += lw[k] * row[k];
  style[b * 512 + c] = acc * 0.04419417382415922f + ab[c];
}

// ---- merged: W2 pack (bf16, [o*9+kp][c]) + dcoef[b,o] ------------------------
__global__ __launch_bounds__(256) void k_wprep(const float* __restrict__ cw,
                                               const float* __restrict__ style,
                                               float* __restrict__ dcoef,
                                               u16* __restrict__ W2) {
  __shared__ u16 lw[4608];
  __shared__ float wsq[512];
  const int o = blockIdx.x, t = threadIdx.x;
  const float* src = cw + (size_t)o * 4608;
  for (int v = t; v < 4608; v += 256) {
    unsigned c = (unsigned)v / 9u;
    unsigned kp = (unsigned)v % 9u;
    lw[kp * 512 + c] = f2bf(src[v]);
  }
  for (int c = t; c < 512; c += 256) {
    const float* p = src + (size_t)c * 9;
    float s = 0.f;
#pragma unroll
    for (int k = 0; k < 9; ++k) {
      float v = p[k];
      s += v * v;
    }
    wsq[c] = s;
  }
  __syncthreads();
  u16* dst = W2 + (size_t)o * 4608;
  for (int v = t; v < 576; v += 256)
    *(u16x8*)(dst + v * 8) = *(const u16x8*)(lw + v * 8);
  const int w = t >> 6, l = t & 63;
  for (int b = w; b < NB; b += 4) {
    float part = 0.f;
#pragma unroll
    for (int c = l; c < 512; c += 64) {
      float st = style[b * 512 + c];
      part += st * st * wsq[c];
    }
#pragma unroll
    for (int off = 32; off; off >>= 1) part += __shfl_down(part, off, 64);
    if (l == 0) dcoef[b * 512 + o] = 1.0f / sqrtf(part + 1e-8f);
  }
}

// ---- xT[b,s,c] = bf16(x[b,c,s] * style[b,c])  (LDS 64x64 transpose) ----------
__global__ __launch_bounds__(256) void k_xt(const float* __restrict__ x,
                                            const float* __restrict__ style,
                                            u16* __restrict__ xT) {
  __shared__ u16 tile[64 * 66];
  const int b = blockIdx.z, c0 = blockIdx.y << 6, s0 = blockIdx.x << 6;
  const int t = threadIdx.x;
#pragma unroll
  for (int i = 0; i < 16; ++i) {
    int e = i * 256 + t;
    int cc = e >> 6, ss = e & 63;
    int c = c0 + cc;
    float v = x[(size_t)(b * 512 + c) * 1024 + s0 + ss] * style[b * 512 + c];
    tile[cc * 66 + ss] = f2bf(v);
  }
  __syncthreads();
#pragma unroll
  for (int e = 0; e < 2; ++e) {
    int idx = e * 256 + t;          // 512 = 64 rows x 8 col-groups
    int sc = idx >> 3;
    int cg = (idx & 7) << 3;
    u16x8 v;
#pragma unroll
    for (int g = 0; g < 8; ++g) v[g] = tile[(cg + g) * 66 + sc];
    *(u16x8*)(xT + (size_t)(b * 1024 + s0 + sc) * 512 + c0 + cg) = v;
  }
}

// ---- GEMM: Z[4608 x 16384] = W2[4608 x 512] * xT[16384 x 512]^T --------------
// 256x256 tile, BK=32, 8 waves (2M x 4N, each 128x64 of C), 16x16x32 bf16 MFMA.
// 4-buffer LDS ring, 2-K-tile-deep async prefetch, counted vmcnt(4) boundary
// waits, raw s_barrier, setprio(1) around each 16-MFMA cluster.
// Chunk swizzle (slot s at row r holds k-chunk (s+(r>>1))&3) applied to the
// global staging source; read slot folds to per-lane constant sk8.
__global__ __launch_bounds__(512, 2) void k_gemm(const u16* __restrict__ W2,
                                                 const u16* __restrict__ xT,
                                                 u16* __restrict__ Z) {
  __shared__ u16 At[4][8192];  // [buf][256 rows x 32 k], 16 KiB each
  __shared__ u16 Bt[4][8192];
  const int t = threadIdx.x;
  const int m0 = blockIdx.y << 8;
  const int n0 = blockIdx.x << 8;
  const int l = t & 63;
  const int w = t >> 6;        // wave 0..7
  const int wm = w >> 2;       // 0..1  (M half: 128 rows)
  const int wn = w & 3;        // 0..3  (N quarter: 64 cols)
  const int lrow = l & 15;
  const int lk = l >> 4;       // k-chunk 0..3

  // staging: thread covers LDS (row q*128 + (t>>2), slot t&3); the global
  // source chunk is pre-swizzled: (slot + (row>>1)) & 3 (q*128 is 0 mod 8).
  const int sr = t >> 2;
  const int sch = ((t & 3) + (sr >> 1)) & 3;
  const u16* gA = W2 + (size_t)(m0 + sr) * 512 + (sch << 3);
  const u16* gB = xT + (size_t)(n0 + sr) * 512 + (sch << 3);
  const int wb = w << 9;       // per-wave LDS base (u16): 64 lanes x 8 u16

  // read-side swizzled chunk offset: slot = (lk - (row>>1)) & 3; row>>1 mod 4
  // reduces to lrow>>1 for all fragment rows used below.
  const int sk8 = ((lk - (lrow >> 1)) & 3) << 3;
  const int arow = (wm << 7) + lrow;
  const int brow = (wn << 6) + lrow;

  f32x4 acc[8][4] = {};

#define STAGE_A(nb_, kt_)                                   \
  async16(&At[nb_][wb], gA + (kt_) * 32);                   \
  async16(&At[nb_][4096 + wb], gA + (kt_) * 32 + 65536)
#define STAGE_B(nb_, kt_)                                   \
  async16(&Bt[nb_][wb], gB + (kt_) * 32);                   \
  async16(&Bt[nb_][4096 + wb], gB + (kt_) * 32 + 65536)

  // prologue: tiles 0 and 1 in flight; wait only for tile 0 (counted).
  STAGE_A(0, 0);
  STAGE_B(0, 0);
  STAGE_A(1, 1);
  STAGE_B(1, 1);
  asm volatile("s_waitcnt vmcnt(4)" ::: "memory");
  asm volatile("s_barrier" ::: "memory");

  for (int kt = 0; kt < 16; ++kt) {
    const int buf = kt & 3;
    const int nb = (kt + 2) & 3;  // ring slot freed at end of tile kt-2
    const u16* Ab = At[buf];
    const u16* Bb = Bt[buf];
    bf16x8 av[4], bv[4], av2[4];

    // ---- phase 0: this wave's C rows 0-63 ----
#pragma unroll
    for (int i = 0; i < 4; ++i)
      av[i] = *(const bf16x8*)(Ab + (arow + i * 16) * 32 + sk8);
#pragma unroll
    for (int j = 0; j < 4; ++j)
      bv[j] = *(const bf16x8*)(Bb + (brow + j * 16) * 32 + sk8);
    if (kt < 14) { STAGE_A(nb, kt + 2); }
    asm volatile("s_barrier" ::: "memory");
    asm volatile("s_waitcnt lgkmcnt(0)" ::: "memory");
    __builtin_amdgcn_sched_barrier(0);
    __builtin_amdgcn_s_setprio(1);
#pragma unroll
    for (int i = 0; i < 4; ++i)
#pragma unroll
      for (int j = 0; j < 4; ++j)
        acc[i][j] = __builtin_amdgcn_mfma_f32_16x16x32_bf16(av[i], bv[j], acc[i][j], 0, 0, 0);
    __builtin_amdgcn_s_setprio(0);
    asm volatile("s_barrier" ::: "memory");

    // ---- phase 1: this wave's C rows 64-127 (bv reused from registers) ----
#pragma unroll
    for (int i = 0; i < 4; ++i)
      av2[i] = *(const bf16x8*)(Ab + (arow + 64 + i * 16) * 32 + sk8);
    if (kt < 14) { STAGE_B(nb, kt + 2); }
    asm volatile("s_barrier" ::: "memory");
    asm volatile("s_waitcnt lgkmcnt(0)" ::: "memory");
    __builtin_amdgcn_sched_barrier(0);
    __builtin_amdgcn_s_setprio(1);
#pragma unroll
    for (int i = 0; i < 4; ++i)
#pragma unroll
      for (int j = 0; j < 4; ++j)
        acc[i + 4][j] = __builtin_amdgcn_mfma_f32_16x16x32_bf16(av2[i], bv[j], acc[i + 4][j], 0, 0, 0);
    __builtin_amdgcn_s_setprio(0);

    // tile boundary: retire tile kt+1's 4 loads; keep tile kt+2's in flight.
    if (kt < 14) {
      asm volatile("s_waitcnt vmcnt(4)" ::: "memory");
    } else if (kt == 14) {
      asm volatile("s_waitcnt vmcnt(0)" ::: "memory");
    }
    asm volatile("s_barrier" ::: "memory");
  }
#undef STAGE_A
#undef STAGE_B

  const int mr = m0 + (wm << 7) + (lk << 2);
  const int nc = n0 + (wn << 6) + lrow;
#pragma unroll
  for (int i = 0; i < 8; ++i)
#pragma unroll
    for (int j = 0; j < 4; ++j)
#pragma unroll
      for (int r = 0; r < 4; ++r)
        Z[(size_t)(mr + i * 16 + r) * 16384 + nc + j * 16] = f2bf(acc[i][j][r]);
}

// ---- scatter: polyphase separable FIR + epilogue -----------------------------
__global__ __launch_bounds__(256) void k_scatter(
    const u16* __restrict__ Z, const float* __restrict__ dcoef,
    const float* __restrict__ noise, const float* __restrict__ nstr,
    const float* __restrict__ bias, float* __restrict__ out) {
  __shared__ u16 Zl[9 * 1024];
  __shared__ float Hl[3 * 2048];
  const int o = blockIdx.x;
  const int b = blockIdx.y;
  const int t = threadIdx.x;
  const u16* Zp = Z + (size_t)o * 9 * 16384 + (size_t)b * 1024;
  for (int v = t; v < 1152; v += 256) {
    int kp = v >> 7, off = (v & 127) << 3;
    *(u16x8*)(Zl + kp * 1024 + off) = *(const u16x8*)(Zp + (size_t)kp * 16384 + off);
  }
  __syncthreads();
#pragma unroll
  for (int e = 0; e < 12; ++e) {
    int idx = e * 256 + t;
    int ky = idx >> 10;
    int i = (idx >> 5) & 31;
    int j = idx & 31;
    const u16* P0 = Zl + (ky * 3 + 0) * 1024 + i * 32;
    const u16* P1 = P0 + 1024;
    const u16* P2 = P0 + 2048;
    float Ej = bf2f(P0[j]) + (j >= 1 ? bf2f(P2[j - 1]) : 0.f);
    float Ej1 = (j < 31 ? bf2f(P0[j + 1]) : 0.f) + bf2f(P2[j]);
    float Ojm = j >= 1 ? bf2f(P1[j - 1]) : 0.f;
    float Oj = bf2f(P1[j]);
    float Ojp = j < 31 ? bf2f(P1[j + 1]) : 0.f;
    float* hp = Hl + ky * 2048 + i * 64 + j;
    hp[0] = Ojm + 3.f * Ej + 3.f * Oj + Ej1;
    hp[32] = Ej + 3.f * Oj + 3.f * Ej1 + Ojp;
  }
  __syncthreads();
  const float dc = dcoef[b * 512 + o] * 0.0625f;
  const float ns = nstr[0];
  const float bo = bias[o];
  const int n = t & 63;
  const int i0 = (t >> 6) << 3;
  const int sw = ((n & 1) << 5) | (n >> 1);
  const float* H0 = Hl + sw;
  const float* H1 = Hl + 2048 + sw;
  const float* H2 = Hl + 4096 + sw;
  float h0 = H0[i0 * 64];
  float h1 = H1[i0 * 64];
  float h1p = (i0 > 0) ? H1[(i0 - 1) * 64] : 0.f;
  float h2p = (i0 > 0) ? H2[(i0 - 1) * 64] : 0.f;
  const float* nz = noise + ((size_t)b << 12) + n;
  float* op = out + (((size_t)(b * 512 + o)) << 12) + n;
#pragma unroll
  for (int s = 0; s < 8; ++s) {
    int i = i0 + s;
    float h0n = (i < 31) ? H0[(i + 1) * 64] : 0.f;
    float h1n = (i < 31) ? H1[(i + 1) * 64] : 0.f;
    float h2 = H2[i * 64];
    float ev = h1p + 3.f * (h0 + h2p) + 3.f * h1 + (h0n + h2);
    float od = (h0 + h2p) + 3.f * h1 + 3.f * (h0n + h2) + h1n;
    int m = 2 * i;
    float v0 = ev * dc + nz[(size_t)m * 64] * ns + bo;
    v0 = (v0 > 0.f ? v0 : 0.2f * v0) * 1.4142135623730951f;
    v0 = fminf(fmaxf(v0, -256.f), 256.f);
    op[(size_t)m * 64] = v0;
    float v1 = od * dc + nz[(size_t)(m + 1) * 64] * ns + bo;
    v1 = (v1 > 0.f ? v1 : 0.2f * v1) * 1.4142135623730951f;
    v1 = fminf(fmaxf(v1, -256.f), 256.f);
    op[(size_t)(m + 1) * 64] = v1;
    h0 = h0n;
    h1p = h1;
    h1 = h1n;
    h2p = h2;
  }
}

extern "C" void kernel_launch(void* const* d_in, const int* in_sizes, int n_in,
                              void* d_out, int out_size, void* d_ws, size_t ws_size,
                              hipStream_t stream) {
  const float* x = (const float*)d_in[0];
  const float* wl = (const float*)d_in[1];
  const float* aw = (const float*)d_in[2];
  const float* ab = (const float*)d_in[3];
  const float* cw = (const float*)d_in[4];
  const float* noise = (const float*)d_in[5];
  const float* nstr = (const float*)d_in[6];
  const float* bias = (const float*)d_in[7];
  float* out = (float*)d_out;

  float* style = (float*)d_ws;
  float* dcoef = style + 8192;
  u16* W2 = (u16*)(dcoef + 8192);
  u16* xT = W2 + 4608 * 512;
  u16* Z = xT + (size_t)16384 * 512;

  k_style<<<dim3(2, 16), 256, 0, stream>>>(wl, aw, ab, style);
  k_wprep<<<dim3(512), 256, 0, stream>>>(cw, style, dcoef, W2);
  k_xt<<<dim3(16, 8, 16), 256, 0, stream>>>(x, style, xT);
  k_gemm<<<dim3(64, 18), 512, 0, stream>>>(W2, xT, Z);
  k_scatter<<<dim3(512, 16), 256, 0, stream>>>(Z, dcoef, noise, nstr, bias, out);
}